// Round 2
// baseline (1318.268 us; speedup 1.0000x reference)
//
#include <hip/hip_runtime.h>

#define N_NODES 10000
#define N_EDGES 160000
#define N_TRI   1600000
#define DM      256
#define CH      64
#define HH      1024

typedef short bf16x8 __attribute__((ext_vector_type(8)));
typedef float f32x4  __attribute__((ext_vector_type(4)));

__device__ __forceinline__ unsigned short f2bf(float f) {
  unsigned int u = __float_as_uint(f);
  u += 0x7fff + ((u >> 16) & 1);   // RNE
  return (unsigned short)(u >> 16);
}

// ---------------------------------------------------------------- projections
__global__ __launch_bounds__(256) void k_node_proj(
    const float* __restrict__ x, const float* __restrict__ Ws, const float* __restrict__ bs,
    const float* __restrict__ Wd, const float* __restrict__ bd,
    float* __restrict__ xs, float* __restrict__ xd) {
  __shared__ float xl[4][DM];
  int tid = threadIdx.x;
  int n0 = blockIdx.x * 4;
  for (int i = tid; i < 4 * DM; i += 256) xl[i >> 8][i & 255] = x[n0 * DM + i];
  __syncthreads();
  int c = tid & 63, g = tid >> 6;
  float as = bs[c], ad = bd[c];
  for (int d = 0; d < DM; d++) {
    float xv = xl[g][d];
    as += xv * Ws[d * CH + c];
    ad += xv * Wd[d * CH + c];
  }
  int n = n0 + g;
  xs[n * CH + c] = as;
  xd[n * CH + c] = ad;
}

// ye = y@W_edge + b_edge, fused with gather-add -> xij
__global__ __launch_bounds__(256) void k_edge_proj(
    const float* __restrict__ y, const float* __restrict__ We, const float* __restrict__ be,
    const float* __restrict__ xs, const float* __restrict__ xd,
    const int* __restrict__ src, const int* __restrict__ dst,
    float* __restrict__ xij) {
  __shared__ float yl[16][DM];
  int tid = threadIdx.x;
  int e0 = blockIdx.x * 16;
  for (int i = tid; i < 16 * DM; i += 256) yl[i >> 8][i & 255] = y[e0 * DM + i];
  __syncthreads();
  int c = tid & 63, g = tid >> 6;
  float acc[4];
#pragma unroll
  for (int s = 0; s < 4; s++) acc[s] = be[c];
  for (int d = 0; d < DM; d += 4) {
    float w0 = We[(d + 0) * CH + c];
    float w1 = We[(d + 1) * CH + c];
    float w2 = We[(d + 2) * CH + c];
    float w3 = We[(d + 3) * CH + c];
#pragma unroll
    for (int s = 0; s < 4; s++) {
      const float4 yv = *(const float4*)&yl[g * 4 + s][d];
      acc[s] += yv.x * w0 + yv.y * w1 + yv.z * w2 + yv.w * w3;
    }
  }
#pragma unroll
  for (int s = 0; s < 4; s++) {
    int e = e0 + g * 4 + s;
    xij[e * CH + c] = acc[s] + xs[src[e] * CH + c] + xd[dst[e] * CH + c];
  }
}

// ---------------------------------------------------------------- rnorm (padded float4 for 1-inst gathers)
__global__ void k_rnorm(const float* __restrict__ r, float4* __restrict__ rn4) {
  int e = blockIdx.x * 256 + threadIdx.x;
  if (e >= N_EDGES) return;
  float a = r[e * 3 + 0], b = r[e * 3 + 1], c = r[e * 3 + 2];
  float inv = rsqrtf(a * a + b * b + c * c);
  rn4[e] = (float4){-a * inv, -b * inv, -c * inv, 0.f};
}

// ---------------------------------------------------------------- per-triplet theta
__global__ __launch_bounds__(256) void k_theta(
    const float4* __restrict__ rn4, const int* __restrict__ tsrc, const int* __restrict__ tdst,
    float* __restrict__ theta) {
  int t = blockIdx.x * 256 + threadIdx.x;
  if (t >= N_TRI) return;
  float4 a = rn4[tsrc[t]];
  float4 b = rn4[tdst[t]];
  float c = a.x * b.x + a.y * b.y + a.z * b.z;
  c = fminf(fmaxf(c, -1.0f + 1e-6f), 1.0f - 1e-6f);
  theta[t] = acosf(c);
}

// ---------------------------------------------------------------- counting sort by tdst
__global__ void k_hist(const int* __restrict__ tdst, int* __restrict__ cnt) {
  int t = blockIdx.x * 256 + threadIdx.x;
  if (t < N_TRI) atomicAdd(&cnt[tdst[t]], 1);
}

__global__ __launch_bounds__(256) void k_scan_sum(const int* __restrict__ cnt,
                                                  int* __restrict__ bsum, int n) {
  __shared__ int s[256];
  int b = blockIdx.x, tid = threadIdx.x;
  int tot = 0;
#pragma unroll
  for (int i = 0; i < 8; i++) {
    int idx = b * 2048 + i * 256 + tid;
    if (idx < n) tot += cnt[idx];
  }
  s[tid] = tot;
  __syncthreads();
  for (int off = 128; off > 0; off >>= 1) {
    if (tid < off) s[tid] += s[tid + off];
    __syncthreads();
  }
  if (tid == 0) bsum[b] = s[0];
}

__global__ void k_scan_top(int* __restrict__ bsum, int nb, int* __restrict__ start_last) {
  if (threadIdx.x == 0) {
    int run = 0;
    for (int i = 0; i < nb; i++) {
      int v = bsum[i];
      bsum[i] = run;
      run += v;
    }
    *start_last = run;  // == N_TRI
  }
}

__global__ __launch_bounds__(256) void k_scan_apply(const int* __restrict__ cnt,
                                                    const int* __restrict__ bsum,
                                                    int* __restrict__ start,
                                                    int* __restrict__ cur, int n) {
  __shared__ int s[256];
  int b = blockIdx.x, tid = threadIdx.x;
  int base = b * 2048 + tid * 8;
  int loc[8];
  int tot = 0;
#pragma unroll
  for (int i = 0; i < 8; i++) {
    int idx = base + i;
    int v = (idx < n) ? cnt[idx] : 0;
    loc[i] = tot;
    tot += v;
  }
  s[tid] = tot;
  __syncthreads();
  for (int off = 1; off < 256; off <<= 1) {
    int t2 = 0;
    if (tid >= off) t2 = s[tid - off];
    __syncthreads();
    if (tid >= off) s[tid] += t2;
    __syncthreads();
  }
  int excl = s[tid] - tot + bsum[b];
#pragma unroll
  for (int i = 0; i < 8; i++) {
    int idx = base + i;
    if (idx < n) {
      int v = excl + loc[i];
      start[idx] = v;
      cur[idx] = v;
    }
  }
}

__global__ void k_scatter(const int* __restrict__ tdst, int* __restrict__ cur,
                          int* __restrict__ sorted) {
  int t = blockIdx.x * 256 + threadIdx.x;
  if (t < N_TRI) {
    int p = atomicAdd(&cur[tdst[t]], 1);
    sorted[p] = t;
  }
}

// ---------------------------------------------------------------- fused triplet logits + segment softmax + weighted gather
__global__ __launch_bounds__(256) void k_attn_ft(
    const int* __restrict__ start, const int* __restrict__ sorted,
    const float* __restrict__ theta, const int* __restrict__ tsrc,
    const float* __restrict__ xij, const float* __restrict__ attn,
    unsigned short* __restrict__ ft) {
  int tid = threadIdx.x;
  int e = blockIdx.x * 4 + (tid >> 6);
  int lane = tid & 63;
  float lanef = (float)lane;
  int beg = start[e], end = start[e + 1];
  int deg = end - beg;
  float xd = xij[e * CH + lane];
  float av = attn[lane];
  float m = -1e30f, den = 0.f, acc = 0.f;
  if (deg > 0 && deg <= 64) {
    int ts_ = 0;
    float th_ = 0.f;
    if (lane < deg) {
      int t = sorted[beg + lane];
      ts_ = tsrc[t];
      th_ = theta[t];
    }
    int ts_cur = __shfl(ts_, 0);
    float th_cur = __shfl(th_, 0);
    float xs_cur = xij[ts_cur * CH + lane];
    for (int i = 0; i < deg; i++) {
      float th_nxt = 0.f, xs_nxt = 0.f;
      if (i + 1 < deg) {
        int ts_nxt = __shfl(ts_, i + 1);
        th_nxt = __shfl(th_, i + 1);
        xs_nxt = xij[ts_nxt * CH + lane];   // prefetch next row
      }
      float v = __cosf(th_cur * lanef) + xs_cur + xd;
      float sv = v / (1.f + __expf(-v));
      float contrib = sv * av;
#pragma unroll
      for (int off = 32; off; off >>= 1) contrib += __shfl_xor(contrib, off);
      float mn = fmaxf(m, contrib);
      float scale = __expf(m - mn);        // 0 on first iter (m=-1e30)
      float p = __expf(contrib - mn);
      den = den * scale + p;
      acc = acc * scale + p * xs_cur;
      m = mn;
      th_cur = th_nxt;
      xs_cur = xs_nxt;
    }
  } else if (deg > 64) {
    for (int i = 0; i < deg; i++) {
      int t = sorted[beg + i];
      int ts = tsrc[t];
      float th = theta[t];
      float xs = xij[ts * CH + lane];
      float v = __cosf(th * lanef) + xs + xd;
      float sv = v / (1.f + __expf(-v));
      float contrib = sv * av;
#pragma unroll
      for (int off = 32; off; off >>= 1) contrib += __shfl_xor(contrib, off);
      float mn = fmaxf(m, contrib);
      float scale = __expf(m - mn);
      float p = __expf(contrib - mn);
      den = den * scale + p;
      acc = acc * scale + p * xs;
      m = mn;
    }
  }
  ft[e * CH + lane] = f2bf(deg > 0 ? acc / den : 0.f);
}

// ---------------------------------------------------------------- weight prep
// W1P: hidden-row-permuted bf16 W1 so that swapped-GEMM1's C/D fragment is
// directly the A fragment of GEMM2 (k=32 over a 32-hidden block).
// row index (hb*2 + t)*16 + i  ->  hidden = hb*32 + 8*(i>>2) + 4*t + (i&3),
// k (=C dim) contiguous.
__global__ __launch_bounds__(256) void k_prep_w1p(const float* __restrict__ W1,
                                                  unsigned short* __restrict__ W1P) {
  int idx = blockIdx.x * 256 + threadIdx.x;   // 64*1024 total
  int k = idx & 63, row = idx >> 6;
  int i = row & 15, t = (row >> 4) & 1, hb = row >> 5;
  int hidden = hb * 32 + ((i >> 2) << 3) + (t << 2) + (i & 3);
  W1P[idx] = f2bf(W1[k * HH + hidden]);
}

__global__ __launch_bounds__(256) void k_prep_w2t(const float* __restrict__ W2,
                                                  unsigned short* __restrict__ W2T) {
  int idx = blockIdx.x * 256 + threadIdx.x;   // idx = n*1024 + k, n<256, k<1024
  int n = idx >> 10, k = idx & 1023;
  W2T[idx] = f2bf(W2[k * DM + n]);
}

// ---------------------------------------------------------------- fused MFMA FFN v2
// out = silu(ft@W1+b1)@W2 + b2.  Barrier-free, LDS-free: GEMM1 computed
// SWAPPED (A = permuted W1 rows, B = ft columns) so its C/D fragment
// (col=lane&15, row=(lane>>4)*4+r) is exactly the A fragment of GEMM2
// (row=lane&15, k=(lane>>4)*8+j) after in-lane bf16 packing.  Each wave owns
// 32 edges x full 256-col output; waves fully independent.
__global__ __launch_bounds__(256, 2) void k_ffn_mfma2(
    const unsigned short* __restrict__ ft, const unsigned short* __restrict__ W1P,
    const float* __restrict__ b1, const unsigned short* __restrict__ W2T,
    const float* __restrict__ b2, float* __restrict__ out) {
  int tid = threadIdx.x;
  int wave = tid >> 6, lane = tid & 63;
  int l16 = lane & 15, q = lane >> 4;
  int ebase = blockIdx.x * 128 + wave * 32;

  // ft B-fragments for GEMM1: [mt][s]  (col = l16 = local edge, k = s*32+q*8+j)
  bf16x8 ftf[2][2];
#pragma unroll
  for (int mt = 0; mt < 2; mt++)
#pragma unroll
    for (int s = 0; s < 2; s++)
      ftf[mt][s] = *(const bf16x8*)&ft[(size_t)(ebase + mt * 16 + l16) * CH + s * 32 + q * 8];

  f32x4 acc[2][16];
#pragma unroll
  for (int mt = 0; mt < 2; mt++)
#pragma unroll
    for (int nt = 0; nt < 16; nt++) acc[mt][nt] = (f32x4){0.f, 0.f, 0.f, 0.f};

  // W1 A-fragments, double-buffered across hb
  bf16x8 w1f[2][2];   // [t][s]
#pragma unroll
  for (int t = 0; t < 2; t++)
#pragma unroll
    for (int s = 0; s < 2; s++)
      w1f[t][s] = *(const bf16x8*)&W1P[(size_t)((t * 16) + l16) * 64 + s * 32 + q * 8];

  for (int hb = 0; hb < 32; hb++) {
    // ---- GEMM1: hT tiles [mt][t]; lane (l16=edge, q) reg r = hidden 8q+4t+r
    f32x4 h[2][2];
#pragma unroll
    for (int mt = 0; mt < 2; mt++)
#pragma unroll
      for (int t = 0; t < 2; t++) {
        f32x4 z = (f32x4){0.f, 0.f, 0.f, 0.f};
        z = __builtin_amdgcn_mfma_f32_16x16x32_bf16(w1f[t][0], ftf[mt][0], z, 0, 0, 0);
        z = __builtin_amdgcn_mfma_f32_16x16x32_bf16(w1f[t][1], ftf[mt][1], z, 0, 0, 0);
        h[mt][t] = z;
      }

    // prefetch next hb's W1 fragments (uniform branch-free via clamp)
    int hbn = (hb < 31) ? hb + 1 : 31;
    bf16x8 w1n[2][2];
#pragma unroll
    for (int t = 0; t < 2; t++)
#pragma unroll
      for (int s = 0; s < 2; s++)
        w1n[t][s] = *(const bf16x8*)&W1P[(size_t)((hbn * 2 + t) * 16 + l16) * 64 + s * 32 + q * 8];

    // ---- bias + silu + pack into GEMM2 A-fragments (in-lane, no shuffles)
    const float4 b1v0 = *(const float4*)&b1[hb * 32 + q * 8];      // t=0: hidden 8q+r
    const float4 b1v1 = *(const float4*)&b1[hb * 32 + q * 8 + 4];  // t=1: hidden 8q+4+r
    union { bf16x8 v; unsigned int u[4]; } pa[2];
#pragma unroll
    for (int mt = 0; mt < 2; mt++) {
      float v0 = h[mt][0][0] + b1v0.x, v1 = h[mt][0][1] + b1v0.y;
      float v2 = h[mt][0][2] + b1v0.z, v3 = h[mt][0][3] + b1v0.w;
      float w0 = h[mt][1][0] + b1v1.x, w1 = h[mt][1][1] + b1v1.y;
      float w2 = h[mt][1][2] + b1v1.z, w3 = h[mt][1][3] + b1v1.w;
      float s0 = v0 / (1.f + __expf(-v0)), s1 = v1 / (1.f + __expf(-v1));
      float s2 = v2 / (1.f + __expf(-v2)), s3 = v3 / (1.f + __expf(-v3));
      float t0 = w0 / (1.f + __expf(-w0)), t1 = w1 / (1.f + __expf(-w1));
      float t2 = w2 / (1.f + __expf(-w2)), t3 = w3 / (1.f + __expf(-w3));
      pa[mt].u[0] = ((unsigned int)f2bf(s1) << 16) | f2bf(s0);
      pa[mt].u[1] = ((unsigned int)f2bf(s3) << 16) | f2bf(s2);
      pa[mt].u[2] = ((unsigned int)f2bf(t1) << 16) | f2bf(t0);
      pa[mt].u[3] = ((unsigned int)f2bf(t3) << 16) | f2bf(t2);
    }

    // ---- GEMM2: acc[mt][nt] += pa[mt] (16 edges x 32 h) @ W2[hb block, nt]
#pragma unroll
    for (int ng = 0; ng < 4; ng++) {
      bf16x8 bw[4];
#pragma unroll
      for (int i = 0; i < 4; i++)
        bw[i] = *(const bf16x8*)&W2T[(size_t)((ng * 4 + i) * 16 + l16) * HH + hb * 32 + q * 8];
#pragma unroll
      for (int i = 0; i < 4; i++) {
        acc[0][ng * 4 + i] =
            __builtin_amdgcn_mfma_f32_16x16x32_bf16(pa[0].v, bw[i], acc[0][ng * 4 + i], 0, 0, 0);
        acc[1][ng * 4 + i] =
            __builtin_amdgcn_mfma_f32_16x16x32_bf16(pa[1].v, bw[i], acc[1][ng * 4 + i], 0, 0, 0);
      }
    }

#pragma unroll
    for (int t = 0; t < 2; t++)
#pragma unroll
      for (int s = 0; s < 2; s++) w1f[t][s] = w1n[t][s];
  }

  // ---- epilogue: + b2, fp32 store.  D: col = nt*16+l16 (dm), row = q*4+r (edge)
#pragma unroll
  for (int nt = 0; nt < 16; nt++) {
    float b2v = b2[nt * 16 + l16];
#pragma unroll
    for (int mt = 0; mt < 2; mt++) {
      int erow = ebase + mt * 16 + q * 4;
#pragma unroll
      for (int r = 0; r < 4; r++)
        out[(size_t)(erow + r) * DM + nt * 16 + l16] = acc[mt][nt][r] + b2v;
    }
  }
}

// ----------------------------------------------------------------------------
extern "C" void kernel_launch(void* const* d_in, const int* in_sizes, int n_in,
                              void* d_out, int out_size, void* d_ws, size_t ws_size,
                              hipStream_t stream) {
  (void)in_sizes; (void)n_in; (void)out_size; (void)ws_size;
  const float* x      = (const float*)d_in[0];
  const float* y      = (const float*)d_in[1];
  const float* r      = (const float*)d_in[2];
  const int*   src    = (const int*)d_in[3];
  const int*   dst    = (const int*)d_in[4];
  const int*   tsrc   = (const int*)d_in[5];
  const int*   tdst   = (const int*)d_in[6];
  const float* W_src  = (const float*)d_in[7];
  const float* b_src  = (const float*)d_in[8];
  const float* W_dst  = (const float*)d_in[9];
  const float* b_dst  = (const float*)d_in[10];
  const float* W_edge = (const float*)d_in[11];
  const float* b_edge = (const float*)d_in[12];
  const float* attn   = (const float*)d_in[13];
  const float* W1     = (const float*)d_in[14];
  const float* b1     = (const float*)d_in[15];
  const float* W2     = (const float*)d_in[16];
  const float* b2     = (const float*)d_in[17];
  float* out = (float*)d_out;

  char* wsp = (char*)d_ws;
  auto alloc = [&](size_t bytes) -> char* {
    char* p = wsp;
    wsp += (bytes + 255) & ~(size_t)255;
    return p;
  };
  float* xs     = (float*)alloc((size_t)N_NODES * CH * 4);
  float* xd     = (float*)alloc((size_t)N_NODES * CH * 4);
  float* xij    = (float*)alloc((size_t)N_EDGES * CH * 4);
  float4* rn4   = (float4*)alloc((size_t)N_EDGES * 16);
  float* theta  = (float*)alloc((size_t)N_TRI * 4);
  int*   cnt    = (int*)alloc((size_t)N_EDGES * 4);
  int*   start  = (int*)alloc((size_t)(N_EDGES + 1) * 4);
  int*   cur    = (int*)alloc((size_t)N_EDGES * 4);
  int*   bsum   = (int*)alloc(1024 * 4);
  int*   sorted = (int*)alloc((size_t)N_TRI * 4);
  unsigned short* ftb = (unsigned short*)alloc((size_t)N_EDGES * CH * 2);
  unsigned short* W1P = (unsigned short*)alloc((size_t)CH * HH * 2);
  unsigned short* W2T = (unsigned short*)alloc((size_t)HH * DM * 2);

  const int NB = (N_EDGES + 2047) / 2048;  // 79

  // weight prep (E-independent, tiny)
  k_prep_w1p<<<(CH * HH) / 256, 256, 0, stream>>>(W1, W1P);
  k_prep_w2t<<<(HH * DM) / 256, 256, 0, stream>>>(W2, W2T);

  k_node_proj<<<N_NODES / 4, 256, 0, stream>>>(x, W_src, b_src, W_dst, b_dst, xs, xd);
  k_rnorm<<<N_EDGES / 256, 256, 0, stream>>>(r, rn4);
  k_edge_proj<<<N_EDGES / 16, 256, 0, stream>>>(y, W_edge, b_edge, xs, xd, src, dst, xij);
  k_theta<<<N_TRI / 256, 256, 0, stream>>>(rn4, tsrc, tdst, theta);

  hipMemsetAsync(cnt, 0, (size_t)N_EDGES * 4, stream);
  k_hist<<<N_TRI / 256, 256, 0, stream>>>(tdst, cnt);
  k_scan_sum<<<NB, 256, 0, stream>>>(cnt, bsum, N_EDGES);
  k_scan_top<<<1, 64, 0, stream>>>(bsum, NB, &start[N_EDGES]);
  k_scan_apply<<<NB, 256, 0, stream>>>(cnt, bsum, start, cur, N_EDGES);
  k_scatter<<<N_TRI / 256, 256, 0, stream>>>(tdst, cur, sorted);

  k_attn_ft<<<N_EDGES / 4, 256, 0, stream>>>(start, sorted, theta, tsrc, xij, attn, ftb);
  k_ffn_mfma2<<<N_EDGES / 128, 256, 0, stream>>>(ftb, W1P, b1, W2T, b2, out);
}

// Round 3
// 1228.348 us; speedup vs baseline: 1.0732x; 1.0732x over previous
//
#include <hip/hip_runtime.h>

#define N_NODES 10000
#define N_EDGES 160000
#define N_TRI   1600000
#define DM      256
#define CH      64
#define HH      1024

typedef short bf16x8 __attribute__((ext_vector_type(8)));
typedef float f32x4  __attribute__((ext_vector_type(4)));

__device__ __forceinline__ unsigned short f2bf(float f) {
  unsigned int u = __float_as_uint(f);
  u += 0x7fff + ((u >> 16) & 1);   // RNE
  return (unsigned short)(u >> 16);
}

// ---------------------------------------------------------------- projections
__global__ __launch_bounds__(256) void k_node_proj(
    const float* __restrict__ x, const float* __restrict__ Ws, const float* __restrict__ bs,
    const float* __restrict__ Wd, const float* __restrict__ bd,
    float* __restrict__ xs, float* __restrict__ xd) {
  __shared__ float xl[4][DM];
  int tid = threadIdx.x;
  int n0 = blockIdx.x * 4;
  for (int i = tid; i < 4 * DM; i += 256) xl[i >> 8][i & 255] = x[n0 * DM + i];
  __syncthreads();
  int c = tid & 63, g = tid >> 6;
  float as = bs[c], ad = bd[c];
  for (int d = 0; d < DM; d++) {
    float xv = xl[g][d];
    as += xv * Ws[d * CH + c];
    ad += xv * Wd[d * CH + c];
  }
  int n = n0 + g;
  xs[n * CH + c] = as;
  xd[n * CH + c] = ad;
}

// ye = y@W_edge + b_edge, fused with gather-add -> xij
__global__ __launch_bounds__(256) void k_edge_proj(
    const float* __restrict__ y, const float* __restrict__ We, const float* __restrict__ be,
    const float* __restrict__ xs, const float* __restrict__ xd,
    const int* __restrict__ src, const int* __restrict__ dst,
    float* __restrict__ xij) {
  __shared__ float yl[16][DM];
  int tid = threadIdx.x;
  int e0 = blockIdx.x * 16;
  for (int i = tid; i < 16 * DM; i += 256) yl[i >> 8][i & 255] = y[e0 * DM + i];
  __syncthreads();
  int c = tid & 63, g = tid >> 6;
  float acc[4];
#pragma unroll
  for (int s = 0; s < 4; s++) acc[s] = be[c];
  for (int d = 0; d < DM; d += 4) {
    float w0 = We[(d + 0) * CH + c];
    float w1 = We[(d + 1) * CH + c];
    float w2 = We[(d + 2) * CH + c];
    float w3 = We[(d + 3) * CH + c];
#pragma unroll
    for (int s = 0; s < 4; s++) {
      const float4 yv = *(const float4*)&yl[g * 4 + s][d];
      acc[s] += yv.x * w0 + yv.y * w1 + yv.z * w2 + yv.w * w3;
    }
  }
#pragma unroll
  for (int s = 0; s < 4; s++) {
    int e = e0 + g * 4 + s;
    xij[e * CH + c] = acc[s] + xs[src[e] * CH + c] + xd[dst[e] * CH + c];
  }
}

// ---------------------------------------------------------------- rnorm (padded float4 for 1-inst gathers)
__global__ void k_rnorm(const float* __restrict__ r, float4* __restrict__ rn4) {
  int e = blockIdx.x * 256 + threadIdx.x;
  if (e >= N_EDGES) return;
  float a = r[e * 3 + 0], b = r[e * 3 + 1], c = r[e * 3 + 2];
  float inv = rsqrtf(a * a + b * b + c * c);
  rn4[e] = (float4){-a * inv, -b * inv, -c * inv, 0.f};
}

// ---------------------------------------------------------------- per-triplet theta
__global__ __launch_bounds__(256) void k_theta(
    const float4* __restrict__ rn4, const int* __restrict__ tsrc, const int* __restrict__ tdst,
    float* __restrict__ theta) {
  int t = blockIdx.x * 256 + threadIdx.x;
  if (t >= N_TRI) return;
  float4 a = rn4[tsrc[t]];
  float4 b = rn4[tdst[t]];
  float c = a.x * b.x + a.y * b.y + a.z * b.z;
  c = fminf(fmaxf(c, -1.0f + 1e-6f), 1.0f - 1e-6f);
  theta[t] = acosf(c);
}

// ---------------------------------------------------------------- counting sort by tdst
__global__ void k_hist(const int* __restrict__ tdst, int* __restrict__ cnt) {
  int t = blockIdx.x * 256 + threadIdx.x;
  if (t < N_TRI) atomicAdd(&cnt[tdst[t]], 1);
}

__global__ __launch_bounds__(256) void k_scan_sum(const int* __restrict__ cnt,
                                                  int* __restrict__ bsum, int n) {
  __shared__ int s[256];
  int b = blockIdx.x, tid = threadIdx.x;
  int tot = 0;
#pragma unroll
  for (int i = 0; i < 8; i++) {
    int idx = b * 2048 + i * 256 + tid;
    if (idx < n) tot += cnt[idx];
  }
  s[tid] = tot;
  __syncthreads();
  for (int off = 128; off > 0; off >>= 1) {
    if (tid < off) s[tid] += s[tid + off];
    __syncthreads();
  }
  if (tid == 0) bsum[b] = s[0];
}

__global__ void k_scan_top(int* __restrict__ bsum, int nb, int* __restrict__ start_last) {
  if (threadIdx.x == 0) {
    int run = 0;
    for (int i = 0; i < nb; i++) {
      int v = bsum[i];
      bsum[i] = run;
      run += v;
    }
    *start_last = run;  // == N_TRI
  }
}

__global__ __launch_bounds__(256) void k_scan_apply(const int* __restrict__ cnt,
                                                    const int* __restrict__ bsum,
                                                    int* __restrict__ start,
                                                    int* __restrict__ cur, int n) {
  __shared__ int s[256];
  int b = blockIdx.x, tid = threadIdx.x;
  int base = b * 2048 + tid * 8;
  int loc[8];
  int tot = 0;
#pragma unroll
  for (int i = 0; i < 8; i++) {
    int idx = base + i;
    int v = (idx < n) ? cnt[idx] : 0;
    loc[i] = tot;
    tot += v;
  }
  s[tid] = tot;
  __syncthreads();
  for (int off = 1; off < 256; off <<= 1) {
    int t2 = 0;
    if (tid >= off) t2 = s[tid - off];
    __syncthreads();
    if (tid >= off) s[tid] += t2;
    __syncthreads();
  }
  int excl = s[tid] - tot + bsum[b];
#pragma unroll
  for (int i = 0; i < 8; i++) {
    int idx = base + i;
    if (idx < n) {
      int v = excl + loc[i];
      start[idx] = v;
      cur[idx] = v;
    }
  }
}

__global__ void k_scatter(const int* __restrict__ tdst, int* __restrict__ cur,
                          int* __restrict__ sorted) {
  int t = blockIdx.x * 256 + threadIdx.x;
  if (t < N_TRI) {
    int p = atomicAdd(&cur[tdst[t]], 1);
    sorted[p] = t;
  }
}

// ---------------------------------------------------------------- fused triplet logits + segment softmax + weighted gather
__global__ __launch_bounds__(256) void k_attn_ft(
    const int* __restrict__ start, const int* __restrict__ sorted,
    const float* __restrict__ theta, const int* __restrict__ tsrc,
    const float* __restrict__ xij, const float* __restrict__ attn,
    unsigned short* __restrict__ ft) {
  int tid = threadIdx.x;
  int e = blockIdx.x * 4 + (tid >> 6);
  int lane = tid & 63;
  float lanef = (float)lane;
  int beg = start[e], end = start[e + 1];
  int deg = end - beg;
  float xd = xij[e * CH + lane];
  float av = attn[lane];
  float m = -1e30f, den = 0.f, acc = 0.f;
  if (deg > 0 && deg <= 64) {
    int ts_ = 0;
    float th_ = 0.f;
    if (lane < deg) {
      int t = sorted[beg + lane];
      ts_ = tsrc[t];
      th_ = theta[t];
    }
    int ts_cur = __shfl(ts_, 0);
    float th_cur = __shfl(th_, 0);
    float xs_cur = xij[ts_cur * CH + lane];
    for (int i = 0; i < deg; i++) {
      float th_nxt = 0.f, xs_nxt = 0.f;
      if (i + 1 < deg) {
        int ts_nxt = __shfl(ts_, i + 1);
        th_nxt = __shfl(th_, i + 1);
        xs_nxt = xij[ts_nxt * CH + lane];   // prefetch next row
      }
      float v = __cosf(th_cur * lanef) + xs_cur + xd;
      float sv = v / (1.f + __expf(-v));
      float contrib = sv * av;
#pragma unroll
      for (int off = 32; off; off >>= 1) contrib += __shfl_xor(contrib, off);
      float mn = fmaxf(m, contrib);
      float scale = __expf(m - mn);        // 0 on first iter (m=-1e30)
      float p = __expf(contrib - mn);
      den = den * scale + p;
      acc = acc * scale + p * xs_cur;
      m = mn;
      th_cur = th_nxt;
      xs_cur = xs_nxt;
    }
  } else if (deg > 64) {
    for (int i = 0; i < deg; i++) {
      int t = sorted[beg + i];
      int ts = tsrc[t];
      float th = theta[t];
      float xs = xij[ts * CH + lane];
      float v = __cosf(th * lanef) + xs + xd;
      float sv = v / (1.f + __expf(-v));
      float contrib = sv * av;
#pragma unroll
      for (int off = 32; off; off >>= 1) contrib += __shfl_xor(contrib, off);
      float mn = fmaxf(m, contrib);
      float scale = __expf(m - mn);
      float p = __expf(contrib - mn);
      den = den * scale + p;
      acc = acc * scale + p * xs;
      m = mn;
    }
  }
  ft[e * CH + lane] = f2bf(deg > 0 ? acc / den : 0.f);
}

// ---------------------------------------------------------------- weight prep
// W1P: hidden-row-permuted bf16 W1 so that swapped-GEMM1's C/D fragment is
// directly the A fragment of GEMM2 (k=32 over a 32-hidden block).
// row index (hb*2 + t)*16 + i  ->  hidden = hb*32 + 8*(i>>2) + 4*t + (i&3),
// k (=C dim) contiguous.
__global__ __launch_bounds__(256) void k_prep_w1p(const float* __restrict__ W1,
                                                  unsigned short* __restrict__ W1P) {
  int idx = blockIdx.x * 256 + threadIdx.x;   // 64*1024 total
  int k = idx & 63, row = idx >> 6;
  int i = row & 15, t = (row >> 4) & 1, hb = row >> 5;
  int hidden = hb * 32 + ((i >> 2) << 3) + (t << 2) + (i & 3);
  W1P[idx] = f2bf(W1[k * HH + hidden]);
}

__global__ __launch_bounds__(256) void k_prep_w2t(const float* __restrict__ W2,
                                                  unsigned short* __restrict__ W2T) {
  int idx = blockIdx.x * 256 + threadIdx.x;   // idx = n*1024 + k, n<256, k<1024
  int n = idx >> 10, k = idx & 1023;
  W2T[idx] = f2bf(W2[k * DM + n]);
}

// ---------------------------------------------------------------- fused MFMA FFN v3
// out = silu(ft@W1+b1)@W2 + b2.  Block = 4 waves / 64 edges / full N=256.
// GEMM1 computed SWAPPED (A = permuted W1 rows, B = ft cols) so each wave's
// h fragment (for its OWN 16 edges x 32 hidden) is silu'd + packed IN-LANE
// into the GEMM2 A-fragment, published with ONE ds_write_b128, and shared
// with the other 3 waves (4 conflict-free ds_read_b128 after 1 barrier).
// Each wave then computes its N=64 slice: 4 W2 B-frag loads feed 16 MFMAs
// (4x amortization).  W2 read once per 64 edges (1.28 GB L2 total).
__global__ __launch_bounds__(256, 3) void k_ffn_mfma3(
    const unsigned short* __restrict__ ft, const unsigned short* __restrict__ W1P,
    const float* __restrict__ b1, const unsigned short* __restrict__ W2T,
    const float* __restrict__ b2, float* __restrict__ out) {
  __shared__ __align__(16) unsigned short hbuf[2][4 * 64 * 8];   // 2 x 4KB
  int tid = threadIdx.x;
  int w = tid >> 6, lane = tid & 63;
  int l16 = lane & 15, q = lane >> 4;
  int e0 = blockIdx.x * 64;

  // own ft B-frags (wave w's 16 edges; col = l16 = edge, k = s*32+q*8+j)
  bf16x8 ftf[2];
#pragma unroll
  for (int s = 0; s < 2; s++)
    ftf[s] = *(const bf16x8*)&ft[(size_t)(e0 + w * 16 + l16) * CH + s * 32 + q * 8];

  f32x4 acc[4][4];
#pragma unroll
  for (int mt = 0; mt < 4; mt++)
#pragma unroll
    for (int nt = 0; nt < 4; nt++) acc[mt][nt] = (f32x4){0.f, 0.f, 0.f, 0.f};

  // W1 A-fragments for hb=0
  bf16x8 w1f[2][2];
#pragma unroll
  for (int t = 0; t < 2; t++)
#pragma unroll
    for (int s = 0; s < 2; s++)
      w1f[t][s] = *(const bf16x8*)&W1P[(size_t)(t * 16 + l16) * 64 + s * 32 + q * 8];

  int p = 0;
  for (int hb = 0; hb < 32; hb++) {
    // W2 B-frags for this hb's GEMM2 (issued early; consumed after barrier)
    bf16x8 bw[4];
#pragma unroll
    for (int nt = 0; nt < 4; nt++)
      bw[nt] = *(const bf16x8*)&W2T[(size_t)(w * 64 + nt * 16 + l16) * HH + hb * 32 + q * 8];

    // ---- GEMM1: own 16 edges x 32 hidden (2 hT tiles)
    f32x4 h0 = (f32x4){0.f, 0.f, 0.f, 0.f};
    f32x4 h1 = (f32x4){0.f, 0.f, 0.f, 0.f};
    h0 = __builtin_amdgcn_mfma_f32_16x16x32_bf16(w1f[0][0], ftf[0], h0, 0, 0, 0);
    h0 = __builtin_amdgcn_mfma_f32_16x16x32_bf16(w1f[0][1], ftf[1], h0, 0, 0, 0);
    h1 = __builtin_amdgcn_mfma_f32_16x16x32_bf16(w1f[1][0], ftf[0], h1, 0, 0, 0);
    h1 = __builtin_amdgcn_mfma_f32_16x16x32_bf16(w1f[1][1], ftf[1], h1, 0, 0, 0);

    // ---- bias + silu + in-lane pack into GEMM2 A-frag
    // lane (l16=edge, q) holds hidden {8q+0..3} (t=0) and {8q+4..7} (t=1)
    const float4 bv0 = *(const float4*)&b1[hb * 32 + q * 8];
    const float4 bv1 = *(const float4*)&b1[hb * 32 + q * 8 + 4];
    float v0 = h0[0] + bv0.x, v1 = h0[1] + bv0.y, v2 = h0[2] + bv0.z, v3 = h0[3] + bv0.w;
    float w0 = h1[0] + bv1.x, w1_ = h1[1] + bv1.y, w2 = h1[2] + bv1.z, w3 = h1[3] + bv1.w;
    float s0 = v0 / (1.f + __expf(-v0)), s1 = v1 / (1.f + __expf(-v1));
    float s2 = v2 / (1.f + __expf(-v2)), s3 = v3 / (1.f + __expf(-v3));
    float t0 = w0 / (1.f + __expf(-w0)), t1 = w1_ / (1.f + __expf(-w1_));
    float t2 = w2 / (1.f + __expf(-w2)), t3 = w3 / (1.f + __expf(-w3));
    union { bf16x8 v; unsigned int u[4]; } pa;
    pa.u[0] = ((unsigned int)f2bf(s1) << 16) | f2bf(s0);
    pa.u[1] = ((unsigned int)f2bf(s3) << 16) | f2bf(s2);
    pa.u[2] = ((unsigned int)f2bf(t1) << 16) | f2bf(t0);
    pa.u[3] = ((unsigned int)f2bf(t3) << 16) | f2bf(t2);
    *(bf16x8*)&hbuf[p][(w * 64 + lane) * 8] = pa.v;

    // prefetch next hb's W1 fragments
    int hbn = (hb < 31) ? hb + 1 : 31;
    bf16x8 w1n[2][2];
#pragma unroll
    for (int t = 0; t < 2; t++)
#pragma unroll
      for (int s = 0; s < 2; s++)
        w1n[t][s] = *(const bf16x8*)&W1P[(size_t)((hbn * 2 + t) * 16 + l16) * 64 + s * 32 + q * 8];

    __syncthreads();

    // ---- GEMM2: acc[mt][nt] += pa[mt] (16 edges x k=32) @ W2 slice
    bf16x8 pam[4];
#pragma unroll
    for (int mt = 0; mt < 4; mt++)
      pam[mt] = *(const bf16x8*)&hbuf[p][(mt * 64 + lane) * 8];
#pragma unroll
    for (int nt = 0; nt < 4; nt++)
#pragma unroll
      for (int mt = 0; mt < 4; mt++)
        acc[mt][nt] = __builtin_amdgcn_mfma_f32_16x16x32_bf16(pam[mt], bw[nt], acc[mt][nt], 0, 0, 0);

#pragma unroll
    for (int t = 0; t < 2; t++)
#pragma unroll
      for (int s = 0; s < 2; s++) w1f[t][s] = w1n[t][s];
    p ^= 1;
  }

  // ---- epilogue: + b2, fp32 store.  D: col = w*64+nt*16+l16, row(edge) = q*4+r
#pragma unroll
  for (int nt = 0; nt < 4; nt++) {
    int col = w * 64 + nt * 16 + l16;
    float b2v = b2[col];
#pragma unroll
    for (int mt = 0; mt < 4; mt++) {
      int erow = e0 + mt * 16 + q * 4;
#pragma unroll
      for (int r = 0; r < 4; r++)
        out[(size_t)(erow + r) * DM + col] = acc[mt][nt][r] + b2v;
    }
  }
}

// ----------------------------------------------------------------------------
extern "C" void kernel_launch(void* const* d_in, const int* in_sizes, int n_in,
                              void* d_out, int out_size, void* d_ws, size_t ws_size,
                              hipStream_t stream) {
  (void)in_sizes; (void)n_in; (void)out_size; (void)ws_size;
  const float* x      = (const float*)d_in[0];
  const float* y      = (const float*)d_in[1];
  const float* r      = (const float*)d_in[2];
  const int*   src    = (const int*)d_in[3];
  const int*   dst    = (const int*)d_in[4];
  const int*   tsrc   = (const int*)d_in[5];
  const int*   tdst   = (const int*)d_in[6];
  const float* W_src  = (const float*)d_in[7];
  const float* b_src  = (const float*)d_in[8];
  const float* W_dst  = (const float*)d_in[9];
  const float* b_dst  = (const float*)d_in[10];
  const float* W_edge = (const float*)d_in[11];
  const float* b_edge = (const float*)d_in[12];
  const float* attn   = (const float*)d_in[13];
  const float* W1     = (const float*)d_in[14];
  const float* b1     = (const float*)d_in[15];
  const float* W2     = (const float*)d_in[16];
  const float* b2     = (const float*)d_in[17];
  float* out = (float*)d_out;

  char* wsp = (char*)d_ws;
  auto alloc = [&](size_t bytes) -> char* {
    char* p = wsp;
    wsp += (bytes + 255) & ~(size_t)255;
    return p;
  };
  float* xs     = (float*)alloc((size_t)N_NODES * CH * 4);
  float* xd     = (float*)alloc((size_t)N_NODES * CH * 4);
  float* xij    = (float*)alloc((size_t)N_EDGES * CH * 4);
  float4* rn4   = (float4*)alloc((size_t)N_EDGES * 16);
  float* theta  = (float*)alloc((size_t)N_TRI * 4);
  int*   cnt    = (int*)alloc((size_t)N_EDGES * 4);
  int*   start  = (int*)alloc((size_t)(N_EDGES + 1) * 4);
  int*   cur    = (int*)alloc((size_t)N_EDGES * 4);
  int*   bsum   = (int*)alloc(1024 * 4);
  int*   sorted = (int*)alloc((size_t)N_TRI * 4);
  unsigned short* ftb = (unsigned short*)alloc((size_t)N_EDGES * CH * 2);
  unsigned short* W1P = (unsigned short*)alloc((size_t)CH * HH * 2);
  unsigned short* W2T = (unsigned short*)alloc((size_t)HH * DM * 2);

  const int NB = (N_EDGES + 2047) / 2048;  // 79

  // weight prep (E-independent, tiny)
  k_prep_w1p<<<(CH * HH) / 256, 256, 0, stream>>>(W1, W1P);
  k_prep_w2t<<<(HH * DM) / 256, 256, 0, stream>>>(W2, W2T);

  k_node_proj<<<N_NODES / 4, 256, 0, stream>>>(x, W_src, b_src, W_dst, b_dst, xs, xd);
  k_rnorm<<<N_EDGES / 256, 256, 0, stream>>>(r, rn4);
  k_edge_proj<<<N_EDGES / 16, 256, 0, stream>>>(y, W_edge, b_edge, xs, xd, src, dst, xij);
  k_theta<<<N_TRI / 256, 256, 0, stream>>>(rn4, tsrc, tdst, theta);

  hipMemsetAsync(cnt, 0, (size_t)N_EDGES * 4, stream);
  k_hist<<<N_TRI / 256, 256, 0, stream>>>(tdst, cnt);
  k_scan_sum<<<NB, 256, 0, stream>>>(cnt, bsum, N_EDGES);
  k_scan_top<<<1, 64, 0, stream>>>(bsum, NB, &start[N_EDGES]);
  k_scan_apply<<<NB, 256, 0, stream>>>(cnt, bsum, start, cur, N_EDGES);
  k_scatter<<<N_TRI / 256, 256, 0, stream>>>(tdst, cur, sorted);

  k_attn_ft<<<N_EDGES / 4, 256, 0, stream>>>(start, sorted, theta, tsrc, xij, attn, ftb);
  k_ffn_mfma3<<<N_EDGES / 64, 256, 0, stream>>>(ftb, W1P, b1, W2T, b2, out);
}